// Round 15
// baseline (121.818 us; speedup 1.0000x reference)
//
#include <hip/hip_runtime.h>

// GraphSAGE layer: out = relu([x, mean-agg(x[src]->dst)] @ W^T + b)
// N=50000 nodes, E=600000 edges, D=128.
//
// Round 15: fuse gather+gemm into sage_fused. Wave wid gathers its own 16
// rows into a private padded LDS strip, then runs its MFMA tile on them.
// No __syncthreads (no cross-wave LDS sharing); drops the 2x12.8MB agg
// round-trip, one launch, and the ah buffer.
// Sharded CSR build proven rounds 13-14. Fallbacks: fp32 CSR, fp-atomic.

#define D 128
#define NT 32
#define NTT 16
#define LROW 136   // padded LDS row stride in bf16 (272 B = 17*16: aligned, 2-way banks)

typedef short bf16x8 __attribute__((ext_vector_type(8)));
typedef float f32x4 __attribute__((ext_vector_type(4)));

__device__ __forceinline__ unsigned bf16_rne(float f) {
    unsigned u = __float_as_uint(f);
    return (u + 0x7FFFu + ((u >> 16) & 1u)) >> 16;
}
__device__ __forceinline__ unsigned pack2(float lo, float hi) {
    return bf16_rne(lo) | (bf16_rne(hi) << 16);
}

// --- fused: zero dshard + convert x -> xh + convert W -> Wf (fragment order) ---

__global__ __launch_bounds__(256) void convert_k(
    const float* __restrict__ x, const float* __restrict__ W,
    unsigned short* __restrict__ xh, unsigned short* __restrict__ Wf,
    int* __restrict__ dshard, int ndz4, int x8)
{
    int i = blockIdx.x * 256 + threadIdx.x;
    if (i < ndz4) ((int4*)dshard)[i] = make_int4(0, 0, 0, 0);
    if (i < x8) {
        const float4* I = (const float4*)x;
        float4 a = I[2 * i], c = I[2 * i + 1];
        uint4 r;
        r.x = pack2(a.x, a.y); r.y = pack2(a.z, a.w);
        r.z = pack2(c.x, c.y); r.w = pack2(c.z, c.w);
        ((uint4*)xh)[i] = r;
    } else {
        int t = i - x8;
        if (t >= 4096) return;
        int f = t >> 6, l = t & 63;
        int row = (f >> 3) * 16 + (l & 15);
        int kk  = (f & 7) * 32 + (l >> 4) * 8;
        const float* Ws = W + row * 256 + kk;
        float4 a = *(const float4*)Ws, c = *(const float4*)(Ws + 4);
        uint4 r;
        r.x = pack2(a.x, a.y); r.y = pack2(a.z, a.w);
        r.z = pack2(c.x, c.y); r.w = pack2(c.z, c.w);
        ((uint4*)Wf)[t] = r;
    }
}

// ---------------- sharded CSR build (proven) ----------------

__global__ __launch_bounds__(256) void count_slot(
    const int* __restrict__ dst, int* dshard, int* __restrict__ slot,
    int n_pad, int n_edges)
{
    int e = blockIdx.x * 256 + threadIdx.x;
    if (e >= n_edges) return;
    int s = blockIdx.x & 7;
    int p = atomicAdd(dshard + s * n_pad + dst[e], 1);
    slot[e] = (p << 3) | s;
}

__global__ __launch_bounds__(256) void combine_scan(
    int* dshard, int* __restrict__ deg, int* off, int* bsum, int n_pad, int n)
{
    __shared__ int tmp[256];
    int i = blockIdx.x * 256 + threadIdx.x;
    int run = 0;
    if (i < n) {
#pragma unroll
        for (int s = 0; s < 8; ++s) {
            int c = dshard[s * n_pad + i];
            dshard[s * n_pad + i] = run;
            run += c;
        }
        deg[i] = run;
    }
    tmp[threadIdx.x] = run;
    __syncthreads();
    for (int s = 1; s < 256; s <<= 1) {
        int t = (threadIdx.x >= s) ? tmp[threadIdx.x - s] : 0;
        __syncthreads();
        tmp[threadIdx.x] += t;
        __syncthreads();
    }
    if (i < n) off[i] = tmp[threadIdx.x];
    if (threadIdx.x == 255) bsum[blockIdx.x] = tmp[255];
}

__global__ __launch_bounds__(256) void scan_b(int* bsum, int nb)
{
    __shared__ int tmp[256];
    int v = (threadIdx.x < nb) ? bsum[threadIdx.x] : 0;
    tmp[threadIdx.x] = v;
    __syncthreads();
    for (int s = 1; s < 256; s <<= 1) {
        int t = (threadIdx.x >= s) ? tmp[threadIdx.x - s] : 0;
        __syncthreads();
        tmp[threadIdx.x] += t;
        __syncthreads();
    }
    if (threadIdx.x < nb) bsum[threadIdx.x] = tmp[threadIdx.x];
}

__global__ __launch_bounds__(256) void scan_c2(
    const int* __restrict__ deg, const int* __restrict__ bsum,
    int* off, int* dshard, int n_pad, int n)
{
    int i = blockIdx.x * 256 + threadIdx.x;
    if (i >= n) return;
    int add = (blockIdx.x > 0) ? bsum[blockIdx.x - 1] : 0;
    int e = off[i] - deg[i] + add;
    off[i] = e;
#pragma unroll
    for (int s = 0; s < 8; ++s) dshard[s * n_pad + i] += e;
}

__global__ __launch_bounds__(256) void fill2(
    const int* __restrict__ src, const int* __restrict__ dst,
    const int* __restrict__ slot, const int* __restrict__ dshard,
    int* __restrict__ edge_src, int n_pad, int n_edges)
{
    int e = blockIdx.x * 256 + threadIdx.x;
    if (e >= n_edges) return;
    int sp = slot[e];
    int pos = dshard[(sp & 7) * n_pad + dst[e]] + (sp >> 3);
    edge_src[pos] = src[e];
}

// ------------- fused gather + MFMA GEMM (no barriers) -------------
// Wave wid: gathers nodes m0..m0+15 into its private LDS strip, then
// computes out[m0..m0+15][0..127] = relu([x|agg] @ W^T + b) via MFMA.

__global__ __launch_bounds__(256) void sage_fused(
    const unsigned short* __restrict__ xh, const int* __restrict__ edge_src,
    const int* __restrict__ off, const int* __restrict__ deg,
    const unsigned short* __restrict__ Wf, const float* __restrict__ bias,
    float* __restrict__ out, int n_nodes)
{
    __shared__ unsigned short sa[64 * LROW];   // 4 waves x 16 rows, padded

    int wid  = threadIdx.x >> 6;
    int lane = threadIdx.x & 63;
    int g    = lane >> 4;          // edge sub-group 0..3
    int dl   = (lane & 15) * 8;    // bf16 slice start in row
    int m0   = blockIdx.x * 64 + wid * 16;

    unsigned short* my = sa + wid * 16 * LROW;

    // ---- gather phase: 16 nodes, wave-private ----
    for (int t = 0; t < 16; ++t) {
        int n = m0 + t;
        if (n >= n_nodes) break;               // wave-uniform
        int dg   = deg[n];
        int base = off[n];

        float s[8] = {0.f, 0.f, 0.f, 0.f, 0.f, 0.f, 0.f, 0.f};
        for (int j0 = 0; j0 < dg; j0 += 8) {
            int ja = j0 + g, jb = j0 + 4 + g;
            uint4 A = make_uint4(0u, 0u, 0u, 0u), B = make_uint4(0u, 0u, 0u, 0u);
            if (ja < dg) {
                int sidx = edge_src[base + ja];
                A = *(const uint4*)(xh + (long long)sidx * 128 + dl);
            }
            if (jb < dg) {
                int sidx = edge_src[base + jb];
                B = *(const uint4*)(xh + (long long)sidx * 128 + dl);
            }
            s[0] += __uint_as_float(A.x << 16) + __uint_as_float(B.x << 16);
            s[1] += __uint_as_float(A.x & 0xFFFF0000u) + __uint_as_float(B.x & 0xFFFF0000u);
            s[2] += __uint_as_float(A.y << 16) + __uint_as_float(B.y << 16);
            s[3] += __uint_as_float(A.y & 0xFFFF0000u) + __uint_as_float(B.y & 0xFFFF0000u);
            s[4] += __uint_as_float(A.z << 16) + __uint_as_float(B.z << 16);
            s[5] += __uint_as_float(A.z & 0xFFFF0000u) + __uint_as_float(B.z & 0xFFFF0000u);
            s[6] += __uint_as_float(A.w << 16) + __uint_as_float(B.w << 16);
            s[7] += __uint_as_float(A.w & 0xFFFF0000u) + __uint_as_float(B.w & 0xFFFF0000u);
        }
#pragma unroll
        for (int k = 0; k < 8; ++k) {
            s[k] += __shfl_xor(s[k], 16, 64);
            s[k] += __shfl_xor(s[k], 32, 64);
        }
        if (g == 0) {
            uint4 r;
            if (dg > 0) {
                float inv = 1.0f / (float)dg;
                r.x = pack2(s[0] * inv, s[1] * inv);
                r.y = pack2(s[2] * inv, s[3] * inv);
                r.z = pack2(s[4] * inv, s[5] * inv);
                r.w = pack2(s[6] * inv, s[7] * inv);
            } else {
                r = *(const uint4*)(xh + (long long)n * 128 + dl);
            }
            *(uint4*)(my + t * LROW + dl) = r;
        }
    }
    // no __syncthreads: each wave reads only its own LDS strip; same-wave
    // ds_write -> ds_read ordering is enforced by compiler waitcnts.

    // ---- gemm phase ----
    int arow = m0 + (lane & 15);
    if (arow >= n_nodes) arow = n_nodes - 1;   // clamp loads; stores guarded
    int ka = (lane >> 4) * 8;
    int lr = (lane & 15);

    f32x4 acc[8] = {};
    const unsigned short* xr = xh + (long long)arow * 128;
    const bf16x8* WF = (const bf16x8*)Wf;

#pragma unroll
    for (int ks = 0; ks < 4; ++ks) {           // k = 0..127 (x half, global)
        bf16x8 af = *(const bf16x8*)(xr + ks * 32 + ka);
#pragma unroll
        for (int nt = 0; nt < 8; ++nt) {
            bf16x8 bf = WF[(nt * 8 + ks) * 64 + lane];
            acc[nt] = __builtin_amdgcn_mfma_f32_16x16x32_bf16(af, bf, acc[nt], 0, 0, 0);
        }
    }
#pragma unroll
    for (int ks = 0; ks < 4; ++ks) {           // k = 128..255 (agg half, LDS)
        bf16x8 af = *(const bf16x8*)(my + lr * LROW + ks * 32 + ka);
#pragma unroll
        for (int nt = 0; nt < 8; ++nt) {
            bf16x8 bf = WF[(nt * 8 + 4 + ks) * 64 + lane];
            acc[nt] = __builtin_amdgcn_mfma_f32_16x16x32_bf16(af, bf, acc[nt], 0, 0, 0);
        }
    }

    int jn = lane & 15;
    int orow0 = m0 + (lane >> 4) * 4;
#pragma unroll
    for (int nt = 0; nt < 8; ++nt) {
        int col = nt * 16 + jn;
        float bj = bias[col];
#pragma unroll
        for (int r = 0; r < 4; ++r) {
            int row = orow0 + r;
            if (row < n_nodes) {
                float v = acc[nt][r] + bj;
                out[(long long)row * 128 + col] = v > 0.f ? v : 0.f;
            }
        }
    }
}

// ---------------- fp32 fallback kernels (round-8 proven) ----------------

__global__ __launch_bounds__(256) void edge_count(
    const int* __restrict__ dst, int* deg, int n_edges)
{
    int e = blockIdx.x * 256 + threadIdx.x;
    if (e < n_edges) atomicAdd(deg + dst[e], 1);
}

__global__ __launch_bounds__(256) void scan_a(
    const int* __restrict__ deg, int* off, int* bsum, int n)
{
    __shared__ int tmp[256];
    int i = blockIdx.x * 256 + threadIdx.x;
    int v = (i < n) ? deg[i] : 0;
    tmp[threadIdx.x] = v;
    __syncthreads();
    for (int s = 1; s < 256; s <<= 1) {
        int t = (threadIdx.x >= s) ? tmp[threadIdx.x - s] : 0;
        __syncthreads();
        tmp[threadIdx.x] += t;
        __syncthreads();
    }
    if (i < n) off[i] = tmp[threadIdx.x];
    if (threadIdx.x == 255) bsum[blockIdx.x] = tmp[255];
}

__global__ __launch_bounds__(256) void scan_c(
    const int* __restrict__ deg, const int* __restrict__ bsum,
    int* off, int* cursor, int n)
{
    int i = blockIdx.x * 256 + threadIdx.x;
    if (i >= n) return;
    int add = (blockIdx.x > 0) ? bsum[blockIdx.x - 1] : 0;
    int e = off[i] - deg[i] + add;
    off[i] = e;
    cursor[i] = e;
}

__global__ __launch_bounds__(256) void edge_fill(
    const int* __restrict__ src, const int* __restrict__ dst,
    int* cursor, int* edge_src, int n_edges)
{
    int e = blockIdx.x * 256 + threadIdx.x;
    if (e < n_edges) {
        int p = atomicAdd(cursor + dst[e], 1);
        edge_src[p] = src[e];
    }
}

__global__ __launch_bounds__(256) void sage_gather(
    const float* __restrict__ x, const int* __restrict__ edge_src,
    const int* __restrict__ off, const int* __restrict__ deg,
    float* __restrict__ agg, int n_nodes)
{
    int wid  = threadIdx.x >> 6;
    int lane = threadIdx.x & 63;
    int n = blockIdx.x * 4 + wid;
    if (n >= n_nodes) return;
    int dg   = deg[n];
    int base = off[n];
    const float2* X2 = (const float2*)x;

    float sx = 0.f, sy = 0.f;
    int j = 0;
    for (; j + 1 < dg; j += 2) {
        int s0 = edge_src[base + j];
        int s1 = edge_src[base + j + 1];
        float2 a = X2[(long long)s0 * 64 + lane];
        float2 c = X2[(long long)s1 * 64 + lane];
        sx += a.x + c.x;
        sy += a.y + c.y;
    }
    if (j < dg) {
        float2 a = X2[(long long)edge_src[base + j] * 64 + lane];
        sx += a.x; sy += a.y;
    }
    float2 r;
    if (dg > 0) {
        float inv = 1.0f / (float)dg;
        r.x = sx * inv; r.y = sy * inv;
    } else {
        r = X2[(long long)n * 64 + lane];
    }
    ((float2*)agg)[(long long)n * 64 + lane] = r;
}

__global__ __launch_bounds__(256) void sage_scatter(
    const float* __restrict__ x, const int* __restrict__ src,
    const int* __restrict__ dst, float* out_sum, int* deg, int n_edges)
{
    long long gid = (long long)blockIdx.x * 256 + threadIdx.x;
    long long total = (long long)n_edges * 32;
    if (gid >= total) return;
    int e  = (int)(gid >> 5);
    int d4 = (int)(gid & 31);
    int s  = src[e];
    int dd = dst[e];
    float4 xv = ((const float4*)x)[s * 32 + d4];
    float* o = out_sum + (long long)dd * D + d4 * 4;
    atomicAdd(o + 0, xv.x);
    atomicAdd(o + 1, xv.y);
    atomicAdd(o + 2, xv.z);
    atomicAdd(o + 3, xv.w);
    if (d4 == 0) atomicAdd(deg + dd, 1);
}

__global__ __launch_bounds__(256) void sage_finalize(
    const float* __restrict__ x, const int* __restrict__ deg,
    float* out, int n_nodes)
{
    int gid = blockIdx.x * 256 + threadIdx.x;
    int total = n_nodes * 32;
    if (gid >= total) return;
    int n = gid >> 5;
    int dg = deg[n];
    float4 v = ((float4*)out)[gid];
    if (dg > 0) {
        float inv = 1.0f / (float)dg;
        v.x *= inv; v.y *= inv; v.z *= inv; v.w *= inv;
    } else {
        v = ((const float4*)x)[gid];
    }
    ((float4*)out)[gid] = v;
}

__global__ __launch_bounds__(256) void sage_gemm(
    const float* __restrict__ x, const float* __restrict__ W,
    const float* __restrict__ b, const float* agg, float* out, int n_nodes)
{
    __shared__ float4 sx[NT * 32];
    __shared__ float4 sa2[NT * 32];

    int tid = threadIdx.x;
    int base_row = blockIdx.x * NT;

    for (int i = tid; i < NT * 32; i += 256) {
        int r = i >> 5, c = i & 31;
        int n = base_row + r; if (n >= n_nodes) n = n_nodes - 1;
        sx[i] = ((const float4*)x)[(long long)n * 32 + c];
        sa2[i] = ((const float4*)agg)[(long long)n * 32 + c];
    }
    __syncthreads();

    int j   = tid & 127;
    int sub = tid >> 7;
    int rbase = sub * NTT;

    const float4* W4 = (const float4*)W;
    float acc[NTT];
#pragma unroll
    for (int i = 0; i < NTT; ++i) acc[i] = 0.f;

#pragma unroll 4
    for (int k4 = 0; k4 < 32; ++k4) {
        float4 wx = W4[j * 64 + k4];
        float4 wa = W4[j * 64 + 32 + k4];
#pragma unroll
        for (int nn = 0; nn < NTT; ++nn) {
            float4 hx = sx[(rbase + nn) * 32 + k4];
            float4 ha = sa2[(rbase + nn) * 32 + k4];
            acc[nn] += wx.x * hx.x + wx.y * hx.y + wx.z * hx.z + wx.w * hx.w
                     + wa.x * ha.x + wa.y * ha.y + wa.z * ha.z + wa.w * ha.w;
        }
    }

    float bj = b[j];
#pragma unroll
    for (int nn = 0; nn < NTT; ++nn) {
        int n = base_row + rbase + nn;
        if (n < n_nodes) {
            float v = acc[nn] + bj;
            out[(long long)n * D + j] = v > 0.f ? v : 0.f;
        }
    }
}

extern "C" void kernel_launch(void* const* d_in, const int* in_sizes, int n_in,
                              void* d_out, int out_size, void* d_ws, size_t ws_size,
                              hipStream_t stream) {
    const float* x  = (const float*)d_in[0];
    const float* W  = (const float*)d_in[1];
    const float* b  = (const float*)d_in[2];
    const int* src  = (const int*)d_in[3];
    const int* dst  = (const int*)d_in[4];
    float* out = (float*)d_out;

    int n_nodes = in_sizes[0] / D;
    int n_edges = in_sizes[3];

    int n_pad = (n_nodes + 255) & ~255;
    int e_pad = (n_edges + 3) & ~3;
    int nblocks_scan = (n_nodes + 255) / 256;

    // ws layout (ints): dshard(8*n_pad) | slot(e_pad) | off(n_pad) | deg(n_pad)
    //                 | bsum(1024) | edge_src(e_pad)
    //   then (bf16): x_bf16 (N*128) | W_frag(32768)
    size_t need_csr  = ((size_t)10 * n_pad + 2 * (size_t)e_pad + 1024) * sizeof(int);
    size_t need_bf16 = need_csr + ((size_t)n_nodes * D + 32768) * sizeof(unsigned short);
    bool scan_ok = (nblocks_scan <= 256);
    bool bf16_ok = scan_ok && (ws_size >= need_bf16);
    bool csr_ok  = scan_ok && (ws_size >= need_csr);

    int* dshard   = (int*)d_ws;               // 8*n_pad
    int* slot     = dshard + 8 * (size_t)n_pad;
    int* off      = slot + e_pad;
    int* deg      = off + n_pad;
    int* bsum     = deg + n_pad;
    int* edge_src = bsum + 1024;

    int eblocks = (n_edges + 255) / 256;

    if (bf16_ok) {
        unsigned short* xh = (unsigned short*)(edge_src + e_pad);
        unsigned short* Wf = xh + (size_t)n_nodes * D;

        // fused: zero dshard + x->bf16 + W->fragment-order bf16
        int x8 = n_nodes * D / 8;
        int ndz4 = (8 * n_pad) / 4;
        convert_k<<<(x8 + 4096 + 255) / 256, 256, 0, stream>>>(
            x, W, xh, Wf, dshard, ndz4, x8);

        // sharded CSR build
        count_slot<<<eblocks, 256, 0, stream>>>(dst, dshard, slot, n_pad, n_edges);
        combine_scan<<<nblocks_scan, 256, 0, stream>>>(dshard, deg, off, bsum, n_pad, n_nodes);
        scan_b<<<1, 256, 0, stream>>>(bsum, nblocks_scan);
        scan_c2<<<nblocks_scan, 256, 0, stream>>>(deg, bsum, off, dshard, n_pad, n_nodes);
        fill2<<<eblocks, 256, 0, stream>>>(src, dst, slot, dshard, edge_src, n_pad, n_edges);

        // fused gather + MFMA GEMM
        sage_fused<<<(n_nodes + 63) / 64, 256, 0, stream>>>(
            xh, edge_src, off, deg, Wf, b, out, n_nodes);
    } else if (csr_ok) {
        // fp32 CSR fallback (round-8 path, non-sharded)
        int* cursor = slot;   // reuse
        hipMemsetAsync(deg, 0, (size_t)n_nodes * sizeof(int), stream);
        edge_count<<<eblocks, 256, 0, stream>>>(dst, deg, n_edges);
        scan_a<<<nblocks_scan, 256, 0, stream>>>(deg, off, bsum, n_nodes);
        scan_b<<<1, 256, 0, stream>>>(bsum, nblocks_scan);
        scan_c<<<nblocks_scan, 256, 0, stream>>>(deg, bsum, off, cursor, n_nodes);
        edge_fill<<<eblocks, 256, 0, stream>>>(src, dst, cursor, edge_src, n_edges);
        sage_gather<<<(n_nodes + 3) / 4, 256, 0, stream>>>(
            x, edge_src, off, deg, out, n_nodes);
        int blocks = (n_nodes + NT - 1) / NT;
        sage_gemm<<<blocks, 256, 0, stream>>>(x, W, b, out, out, n_nodes);
    } else {
        hipMemsetAsync(d_out, 0, (size_t)out_size * sizeof(float), stream);
        hipMemsetAsync(deg, 0, (size_t)n_nodes * sizeof(int), stream);
        long long total = (long long)n_edges * 32;
        int blocks = (int)((total + 255) / 256);
        sage_scatter<<<blocks, 256, 0, stream>>>(x, src, dst, out, deg, n_edges);
        int fblocks = (n_nodes * 32 + 255) / 256;
        sage_finalize<<<fblocks, 256, 0, stream>>>(x, deg, out, n_nodes);
        int gb = (n_nodes + NT - 1) / NT;
        sage_gemm<<<gb, 256, 0, stream>>>(x, W, b, out, out, n_nodes);
    }
}

// Round 16
// 98.750 us; speedup vs baseline: 1.2336x; 1.2336x over previous
//
#include <hip/hip_runtime.h>

// GraphSAGE layer: out = relu([x, mean-agg(x[src]->dst)] @ W^T + b)
// N=50000 nodes, E=600000 edges, D=128.
//
// Round 16: fused gather+gemm v2 — 16-row blocks restore gather TLP.
//  Round-15 fusion regressed because each wave serially gathered 16 nodes
//  (3128 waves total vs round-14's 12500). Now: block = 16 rows (one MFMA
//  M-tile), 4 waves; gather phase = 4 nodes/wave into a shared LDS tile;
//  one barrier; gemm phase = each wave does 2 column-tiles. Grid 3125.
// Sharded CSR build proven rounds 13-14. Fallbacks: fp32 CSR, fp-atomic.

#define D 128
#define NT 32
#define NTT 16
#define LROW 136   // padded LDS row stride in bf16 (272 B)

typedef short bf16x8 __attribute__((ext_vector_type(8)));
typedef float f32x4 __attribute__((ext_vector_type(4)));

__device__ __forceinline__ unsigned bf16_rne(float f) {
    unsigned u = __float_as_uint(f);
    return (u + 0x7FFFu + ((u >> 16) & 1u)) >> 16;
}
__device__ __forceinline__ unsigned pack2(float lo, float hi) {
    return bf16_rne(lo) | (bf16_rne(hi) << 16);
}

// --- fused: zero dshard + convert x -> xh + convert W -> Wf (fragment order) ---

__global__ __launch_bounds__(256) void convert_k(
    const float* __restrict__ x, const float* __restrict__ W,
    unsigned short* __restrict__ xh, unsigned short* __restrict__ Wf,
    int* __restrict__ dshard, int ndz4, int x8)
{
    int i = blockIdx.x * 256 + threadIdx.x;
    if (i < ndz4) ((int4*)dshard)[i] = make_int4(0, 0, 0, 0);
    if (i < x8) {
        const float4* I = (const float4*)x;
        float4 a = I[2 * i], c = I[2 * i + 1];
        uint4 r;
        r.x = pack2(a.x, a.y); r.y = pack2(a.z, a.w);
        r.z = pack2(c.x, c.y); r.w = pack2(c.z, c.w);
        ((uint4*)xh)[i] = r;
    } else {
        int t = i - x8;
        if (t >= 4096) return;
        int f = t >> 6, l = t & 63;
        int row = (f >> 3) * 16 + (l & 15);
        int kk  = (f & 7) * 32 + (l >> 4) * 8;
        const float* Ws = W + row * 256 + kk;
        float4 a = *(const float4*)Ws, c = *(const float4*)(Ws + 4);
        uint4 r;
        r.x = pack2(a.x, a.y); r.y = pack2(a.z, a.w);
        r.z = pack2(c.x, c.y); r.w = pack2(c.z, c.w);
        ((uint4*)Wf)[t] = r;
    }
}

// ---------------- sharded CSR build (proven) ----------------

__global__ __launch_bounds__(256) void count_slot(
    const int* __restrict__ dst, int* dshard, int* __restrict__ slot,
    int n_pad, int n_edges)
{
    int e = blockIdx.x * 256 + threadIdx.x;
    if (e >= n_edges) return;
    int s = blockIdx.x & 7;
    int p = atomicAdd(dshard + s * n_pad + dst[e], 1);
    slot[e] = (p << 3) | s;
}

__global__ __launch_bounds__(256) void combine_scan(
    int* dshard, int* __restrict__ deg, int* off, int* bsum, int n_pad, int n)
{
    __shared__ int tmp[256];
    int i = blockIdx.x * 256 + threadIdx.x;
    int run = 0;
    if (i < n) {
#pragma unroll
        for (int s = 0; s < 8; ++s) {
            int c = dshard[s * n_pad + i];
            dshard[s * n_pad + i] = run;
            run += c;
        }
        deg[i] = run;
    }
    tmp[threadIdx.x] = run;
    __syncthreads();
    for (int s = 1; s < 256; s <<= 1) {
        int t = (threadIdx.x >= s) ? tmp[threadIdx.x - s] : 0;
        __syncthreads();
        tmp[threadIdx.x] += t;
        __syncthreads();
    }
    if (i < n) off[i] = tmp[threadIdx.x];
    if (threadIdx.x == 255) bsum[blockIdx.x] = tmp[255];
}

__global__ __launch_bounds__(256) void scan_b(int* bsum, int nb)
{
    __shared__ int tmp[256];
    int v = (threadIdx.x < nb) ? bsum[threadIdx.x] : 0;
    tmp[threadIdx.x] = v;
    __syncthreads();
    for (int s = 1; s < 256; s <<= 1) {
        int t = (threadIdx.x >= s) ? tmp[threadIdx.x - s] : 0;
        __syncthreads();
        tmp[threadIdx.x] += t;
        __syncthreads();
    }
    if (threadIdx.x < nb) bsum[threadIdx.x] = tmp[threadIdx.x];
}

__global__ __launch_bounds__(256) void scan_c2(
    const int* __restrict__ deg, const int* __restrict__ bsum,
    int* off, int* dshard, int n_pad, int n)
{
    int i = blockIdx.x * 256 + threadIdx.x;
    if (i >= n) return;
    int add = (blockIdx.x > 0) ? bsum[blockIdx.x - 1] : 0;
    int e = off[i] - deg[i] + add;
    off[i] = e;
#pragma unroll
    for (int s = 0; s < 8; ++s) dshard[s * n_pad + i] += e;
}

__global__ __launch_bounds__(256) void fill2(
    const int* __restrict__ src, const int* __restrict__ dst,
    const int* __restrict__ slot, const int* __restrict__ dshard,
    int* __restrict__ edge_src, int n_pad, int n_edges)
{
    int e = blockIdx.x * 256 + threadIdx.x;
    if (e >= n_edges) return;
    int sp = slot[e];
    int pos = dshard[(sp & 7) * n_pad + dst[e]] + (sp >> 3);
    edge_src[pos] = src[e];
}

// ---- fused gather + MFMA GEMM v2: 16-row block, 4 nodes/wave gather ----

__global__ __launch_bounds__(256) void sage_fused16(
    const unsigned short* __restrict__ xh, const int* __restrict__ edge_src,
    const int* __restrict__ off, const int* __restrict__ deg,
    const unsigned short* __restrict__ Wf, const float* __restrict__ bias,
    float* __restrict__ out, int n_nodes)
{
    __shared__ unsigned short sa[16 * LROW];   // one 16-row agg tile

    int wid  = threadIdx.x >> 6;
    int lane = threadIdx.x & 63;
    int g    = lane >> 4;          // edge sub-group 0..3
    int dl   = (lane & 15) * 8;    // bf16 slice start in row
    int m0   = blockIdx.x * 16;

    // ---- gather phase: wave wid -> rows wid*4 .. wid*4+3 ----
#pragma unroll
    for (int t = 0; t < 4; ++t) {
        int r = wid * 4 + t;
        int n = m0 + r;
        if (n < n_nodes) {
            int dg   = deg[n];
            int base = off[n];

            float s[8] = {0.f, 0.f, 0.f, 0.f, 0.f, 0.f, 0.f, 0.f};
            for (int j0 = 0; j0 < dg; j0 += 8) {
                int ja = j0 + g, jb = j0 + 4 + g;
                uint4 A = make_uint4(0u, 0u, 0u, 0u), B = make_uint4(0u, 0u, 0u, 0u);
                if (ja < dg) {
                    int sidx = edge_src[base + ja];
                    A = *(const uint4*)(xh + (long long)sidx * 128 + dl);
                }
                if (jb < dg) {
                    int sidx = edge_src[base + jb];
                    B = *(const uint4*)(xh + (long long)sidx * 128 + dl);
                }
                s[0] += __uint_as_float(A.x << 16) + __uint_as_float(B.x << 16);
                s[1] += __uint_as_float(A.x & 0xFFFF0000u) + __uint_as_float(B.x & 0xFFFF0000u);
                s[2] += __uint_as_float(A.y << 16) + __uint_as_float(B.y << 16);
                s[3] += __uint_as_float(A.y & 0xFFFF0000u) + __uint_as_float(B.y & 0xFFFF0000u);
                s[4] += __uint_as_float(A.z << 16) + __uint_as_float(B.z << 16);
                s[5] += __uint_as_float(A.z & 0xFFFF0000u) + __uint_as_float(B.z & 0xFFFF0000u);
                s[6] += __uint_as_float(A.w << 16) + __uint_as_float(B.w << 16);
                s[7] += __uint_as_float(A.w & 0xFFFF0000u) + __uint_as_float(B.w & 0xFFFF0000u);
            }
#pragma unroll
            for (int k = 0; k < 8; ++k) {
                s[k] += __shfl_xor(s[k], 16, 64);
                s[k] += __shfl_xor(s[k], 32, 64);
            }
            if (g == 0) {
                uint4 rr;
                if (dg > 0) {
                    float inv = 1.0f / (float)dg;
                    rr.x = pack2(s[0] * inv, s[1] * inv);
                    rr.y = pack2(s[2] * inv, s[3] * inv);
                    rr.z = pack2(s[4] * inv, s[5] * inv);
                    rr.w = pack2(s[6] * inv, s[7] * inv);
                } else {
                    rr = *(const uint4*)(xh + (long long)n * 128 + dl);
                }
                *(uint4*)(sa + r * LROW + dl) = rr;
            }
        }
    }
    __syncthreads();

    // ---- gemm phase: wave wid computes col-tiles nt = wid*2, wid*2+1 ----
    int arow = m0 + (lane & 15);
    if (arow >= n_nodes) arow = n_nodes - 1;   // clamp loads; stores guarded
    int ka = (lane >> 4) * 8;
    int lr = lane & 15;

    f32x4 acc[2] = {};
    const unsigned short* xr = xh + (long long)arow * 128;
    const bf16x8* WF = (const bf16x8*)Wf;
    int nt0 = wid * 2;

#pragma unroll
    for (int ks = 0; ks < 4; ++ks) {           // k = 0..127 (x half, global)
        bf16x8 af = *(const bf16x8*)(xr + ks * 32 + ka);
        acc[0] = __builtin_amdgcn_mfma_f32_16x16x32_bf16(af, WF[(nt0 * 8 + ks) * 64 + lane], acc[0], 0, 0, 0);
        acc[1] = __builtin_amdgcn_mfma_f32_16x16x32_bf16(af, WF[((nt0 + 1) * 8 + ks) * 64 + lane], acc[1], 0, 0, 0);
    }
#pragma unroll
    for (int ks = 0; ks < 4; ++ks) {           // k = 128..255 (agg half, LDS)
        bf16x8 af = *(const bf16x8*)(sa + lr * LROW + ks * 32 + ka);
        acc[0] = __builtin_amdgcn_mfma_f32_16x16x32_bf16(af, WF[(nt0 * 8 + 4 + ks) * 64 + lane], acc[0], 0, 0, 0);
        acc[1] = __builtin_amdgcn_mfma_f32_16x16x32_bf16(af, WF[((nt0 + 1) * 8 + 4 + ks) * 64 + lane], acc[1], 0, 0, 0);
    }

    int jn = lane & 15;
    int orow0 = m0 + (lane >> 4) * 4;
#pragma unroll
    for (int q = 0; q < 2; ++q) {
        int col = (nt0 + q) * 16 + jn;
        float bj = bias[col];
#pragma unroll
        for (int r = 0; r < 4; ++r) {
            int row = orow0 + r;
            if (row < n_nodes) {
                float v = acc[q][r] + bj;
                out[(long long)row * 128 + col] = v > 0.f ? v : 0.f;
            }
        }
    }
}

// ---------------- fp32 fallback kernels (round-8 proven) ----------------

__global__ __launch_bounds__(256) void edge_count(
    const int* __restrict__ dst, int* deg, int n_edges)
{
    int e = blockIdx.x * 256 + threadIdx.x;
    if (e < n_edges) atomicAdd(deg + dst[e], 1);
}

__global__ __launch_bounds__(256) void scan_a(
    const int* __restrict__ deg, int* off, int* bsum, int n)
{
    __shared__ int tmp[256];
    int i = blockIdx.x * 256 + threadIdx.x;
    int v = (i < n) ? deg[i] : 0;
    tmp[threadIdx.x] = v;
    __syncthreads();
    for (int s = 1; s < 256; s <<= 1) {
        int t = (threadIdx.x >= s) ? tmp[threadIdx.x - s] : 0;
        __syncthreads();
        tmp[threadIdx.x] += t;
        __syncthreads();
    }
    if (i < n) off[i] = tmp[threadIdx.x];
    if (threadIdx.x == 255) bsum[blockIdx.x] = tmp[255];
}

__global__ __launch_bounds__(256) void scan_c(
    const int* __restrict__ deg, const int* __restrict__ bsum,
    int* off, int* cursor, int n)
{
    int i = blockIdx.x * 256 + threadIdx.x;
    if (i >= n) return;
    int add = (blockIdx.x > 0) ? bsum[blockIdx.x - 1] : 0;
    int e = off[i] - deg[i] + add;
    off[i] = e;
    cursor[i] = e;
}

__global__ __launch_bounds__(256) void edge_fill(
    const int* __restrict__ src, const int* __restrict__ dst,
    int* cursor, int* edge_src, int n_edges)
{
    int e = blockIdx.x * 256 + threadIdx.x;
    if (e < n_edges) {
        int p = atomicAdd(cursor + dst[e], 1);
        edge_src[p] = src[e];
    }
}

__global__ __launch_bounds__(256) void sage_gather(
    const float* __restrict__ x, const int* __restrict__ edge_src,
    const int* __restrict__ off, const int* __restrict__ deg,
    float* __restrict__ agg, int n_nodes)
{
    int wid  = threadIdx.x >> 6;
    int lane = threadIdx.x & 63;
    int n = blockIdx.x * 4 + wid;
    if (n >= n_nodes) return;
    int dg   = deg[n];
    int base = off[n];
    const float2* X2 = (const float2*)x;

    float sx = 0.f, sy = 0.f;
    int j = 0;
    for (; j + 1 < dg; j += 2) {
        int s0 = edge_src[base + j];
        int s1 = edge_src[base + j + 1];
        float2 a = X2[(long long)s0 * 64 + lane];
        float2 c = X2[(long long)s1 * 64 + lane];
        sx += a.x + c.x;
        sy += a.y + c.y;
    }
    if (j < dg) {
        float2 a = X2[(long long)edge_src[base + j] * 64 + lane];
        sx += a.x; sy += a.y;
    }
    float2 r;
    if (dg > 0) {
        float inv = 1.0f / (float)dg;
        r.x = sx * inv; r.y = sy * inv;
    } else {
        r = X2[(long long)n * 64 + lane];
    }
    ((float2*)agg)[(long long)n * 64 + lane] = r;
}

__global__ __launch_bounds__(256) void sage_scatter(
    const float* __restrict__ x, const int* __restrict__ src,
    const int* __restrict__ dst, float* out_sum, int* deg, int n_edges)
{
    long long gid = (long long)blockIdx.x * 256 + threadIdx.x;
    long long total = (long long)n_edges * 32;
    if (gid >= total) return;
    int e  = (int)(gid >> 5);
    int d4 = (int)(gid & 31);
    int s  = src[e];
    int dd = dst[e];
    float4 xv = ((const float4*)x)[s * 32 + d4];
    float* o = out_sum + (long long)dd * D + d4 * 4;
    atomicAdd(o + 0, xv.x);
    atomicAdd(o + 1, xv.y);
    atomicAdd(o + 2, xv.z);
    atomicAdd(o + 3, xv.w);
    if (d4 == 0) atomicAdd(deg + dd, 1);
}

__global__ __launch_bounds__(256) void sage_finalize(
    const float* __restrict__ x, const int* __restrict__ deg,
    float* out, int n_nodes)
{
    int gid = blockIdx.x * 256 + threadIdx.x;
    int total = n_nodes * 32;
    if (gid >= total) return;
    int n = gid >> 5;
    int dg = deg[n];
    float4 v = ((float4*)out)[gid];
    if (dg > 0) {
        float inv = 1.0f / (float)dg;
        v.x *= inv; v.y *= inv; v.z *= inv; v.w *= inv;
    } else {
        v = ((const float4*)x)[gid];
    }
    ((float4*)out)[gid] = v;
}

__global__ __launch_bounds__(256) void sage_gemm(
    const float* __restrict__ x, const float* __restrict__ W,
    const float* __restrict__ b, const float* agg, float* out, int n_nodes)
{
    __shared__ float4 sx[NT * 32];
    __shared__ float4 sa2[NT * 32];

    int tid = threadIdx.x;
    int base_row = blockIdx.x * NT;

    for (int i = tid; i < NT * 32; i += 256) {
        int r = i >> 5, c = i & 31;
        int n = base_row + r; if (n >= n_nodes) n = n_nodes - 1;
        sx[i] = ((const float4*)x)[(long long)n * 32 + c];
        sa2[i] = ((const float4*)agg)[(long long)n * 32 + c];
    }
    __syncthreads();

    int j   = tid & 127;
    int sub = tid >> 7;
    int rbase = sub * NTT;

    const float4* W4 = (const float4*)W;
    float acc[NTT];
#pragma unroll
    for (int i = 0; i < NTT; ++i) acc[i] = 0.f;

#pragma unroll 4
    for (int k4 = 0; k4 < 32; ++k4) {
        float4 wx = W4[j * 64 + k4];
        float4 wa = W4[j * 64 + 32 + k4];
#pragma unroll
        for (int nn = 0; nn < NTT; ++nn) {
            float4 hx = sx[(rbase + nn) * 32 + k4];
            float4 ha = sa2[(rbase + nn) * 32 + k4];
            acc[nn] += wx.x * hx.x + wx.y * hx.y + wx.z * hx.z + wx.w * hx.w
                     + wa.x * ha.x + wa.y * ha.y + wa.z * ha.z + wa.w * ha.w;
        }
    }

    float bj = b[j];
#pragma unroll
    for (int nn = 0; nn < NTT; ++nn) {
        int n = base_row + rbase + nn;
        if (n < n_nodes) {
            float v = acc[nn] + bj;
            out[(long long)n * D + j] = v > 0.f ? v : 0.f;
        }
    }
}

extern "C" void kernel_launch(void* const* d_in, const int* in_sizes, int n_in,
                              void* d_out, int out_size, void* d_ws, size_t ws_size,
                              hipStream_t stream) {
    const float* x  = (const float*)d_in[0];
    const float* W  = (const float*)d_in[1];
    const float* b  = (const float*)d_in[2];
    const int* src  = (const int*)d_in[3];
    const int* dst  = (const int*)d_in[4];
    float* out = (float*)d_out;

    int n_nodes = in_sizes[0] / D;
    int n_edges = in_sizes[3];

    int n_pad = (n_nodes + 255) & ~255;
    int e_pad = (n_edges + 3) & ~3;
    int nblocks_scan = (n_nodes + 255) / 256;

    // ws layout (ints): dshard(8*n_pad) | slot(e_pad) | off(n_pad) | deg(n_pad)
    //                 | bsum(1024) | edge_src(e_pad)
    //   then (bf16): x_bf16 (N*128) | W_frag(32768)
    size_t need_csr  = ((size_t)10 * n_pad + 2 * (size_t)e_pad + 1024) * sizeof(int);
    size_t need_bf16 = need_csr + ((size_t)n_nodes * D + 32768) * sizeof(unsigned short);
    bool scan_ok = (nblocks_scan <= 256);
    bool bf16_ok = scan_ok && (ws_size >= need_bf16);
    bool csr_ok  = scan_ok && (ws_size >= need_csr);

    int* dshard   = (int*)d_ws;               // 8*n_pad
    int* slot     = dshard + 8 * (size_t)n_pad;
    int* off      = slot + e_pad;
    int* deg      = off + n_pad;
    int* bsum     = deg + n_pad;
    int* edge_src = bsum + 1024;

    int eblocks = (n_edges + 255) / 256;

    if (bf16_ok) {
        unsigned short* xh = (unsigned short*)(edge_src + e_pad);
        unsigned short* Wf = xh + (size_t)n_nodes * D;

        // fused: zero dshard + x->bf16 + W->fragment-order bf16
        int x8 = n_nodes * D / 8;
        int ndz4 = (8 * n_pad) / 4;
        convert_k<<<(x8 + 4096 + 255) / 256, 256, 0, stream>>>(
            x, W, xh, Wf, dshard, ndz4, x8);

        // sharded CSR build
        count_slot<<<eblocks, 256, 0, stream>>>(dst, dshard, slot, n_pad, n_edges);
        combine_scan<<<nblocks_scan, 256, 0, stream>>>(dshard, deg, off, bsum, n_pad, n_nodes);
        scan_b<<<1, 256, 0, stream>>>(bsum, nblocks_scan);
        scan_c2<<<nblocks_scan, 256, 0, stream>>>(deg, bsum, off, dshard, n_pad, n_nodes);
        fill2<<<eblocks, 256, 0, stream>>>(src, dst, slot, dshard, edge_src, n_pad, n_edges);

        // fused gather + MFMA GEMM (16-row blocks)
        sage_fused16<<<(n_nodes + 15) / 16, 256, 0, stream>>>(
            xh, edge_src, off, deg, Wf, b, out, n_nodes);
    } else if (csr_ok) {
        // fp32 CSR fallback (round-8 path, non-sharded)
        int* cursor = slot;   // reuse
        hipMemsetAsync(deg, 0, (size_t)n_nodes * sizeof(int), stream);
        edge_count<<<eblocks, 256, 0, stream>>>(dst, deg, n_edges);
        scan_a<<<nblocks_scan, 256, 0, stream>>>(deg, off, bsum, n_nodes);
        scan_b<<<1, 256, 0, stream>>>(bsum, nblocks_scan);
        scan_c<<<nblocks_scan, 256, 0, stream>>>(deg, bsum, off, cursor, n_nodes);
        edge_fill<<<eblocks, 256, 0, stream>>>(src, dst, cursor, edge_src, n_edges);
        sage_gather<<<(n_nodes + 3) / 4, 256, 0, stream>>>(
            x, edge_src, off, deg, out, n_nodes);
        int blocks = (n_nodes + NT - 1) / NT;
        sage_gemm<<<blocks, 256, 0, stream>>>(x, W, b, out, out, n_nodes);
    } else {
        hipMemsetAsync(d_out, 0, (size_t)out_size * sizeof(float), stream);
        hipMemsetAsync(deg, 0, (size_t)n_nodes * sizeof(int), stream);
        long long total = (long long)n_edges * 32;
        int blocks = (int)((total + 255) / 256);
        sage_scatter<<<blocks, 256, 0, stream>>>(x, src, dst, out, deg, n_edges);
        int fblocks = (n_nodes * 32 + 255) / 256;
        sage_finalize<<<fblocks, 256, 0, stream>>>(x, deg, out, n_nodes);
        int gb = (n_nodes + NT - 1) / NT;
        sage_gemm<<<gb, 256, 0, stream>>>(x, W, b, out, out, n_nodes);
    }
}

// Round 18
// 94.069 us; speedup vs baseline: 1.2950x; 1.0498x over previous
//
#include <hip/hip_runtime.h>

// GraphSAGE layer: out = relu([x, mean-agg(x[src]->dst)] @ W^T + b)
// N=50000 nodes, E=600000 edges, D=128.
//
// Round 17 kernel, identical resubmit (round-17 bench died on the recurring
// unresponsive container before compile/run).
//  (a) combine_scan_atomic: CSR segment order is irrelevant, so the ordered
//      cross-block scan (combine_scan+scan_b+scan_c2) collapses into ONE
//      kernel: block LDS scan + one atomicAdd(cursor, blockTotal) per block
//      for base allocation. 7 -> 5 launches.
//  (b) gather unrolled to 16 edges in flight (4 uint4 loads/lane) — mean
//      deg=12 completes in one memory round-trip.
// fused16 structure proven round 16. Fallbacks: fp32 CSR, fp-atomic.

#define D 128
#define NT 32
#define NTT 16
#define LROW 136   // padded LDS row stride in bf16 (272 B)

typedef short bf16x8 __attribute__((ext_vector_type(8)));
typedef float f32x4 __attribute__((ext_vector_type(4)));

__device__ __forceinline__ unsigned bf16_rne(float f) {
    unsigned u = __float_as_uint(f);
    return (u + 0x7FFFu + ((u >> 16) & 1u)) >> 16;
}
__device__ __forceinline__ unsigned pack2(float lo, float hi) {
    return bf16_rne(lo) | (bf16_rne(hi) << 16);
}

// --- fused: zero dshard+cursor + convert x -> xh + convert W -> Wf ---

__global__ __launch_bounds__(256) void convert_k(
    const float* __restrict__ x, const float* __restrict__ W,
    unsigned short* __restrict__ xh, unsigned short* __restrict__ Wf,
    int* __restrict__ dshard, int* __restrict__ cursor, int ndz4, int x8)
{
    int i = blockIdx.x * 256 + threadIdx.x;
    if (i == 0) *cursor = 0;
    if (i < ndz4) ((int4*)dshard)[i] = make_int4(0, 0, 0, 0);
    if (i < x8) {
        const float4* I = (const float4*)x;
        float4 a = I[2 * i], c = I[2 * i + 1];
        uint4 r;
        r.x = pack2(a.x, a.y); r.y = pack2(a.z, a.w);
        r.z = pack2(c.x, c.y); r.w = pack2(c.z, c.w);
        ((uint4*)xh)[i] = r;
    } else {
        int t = i - x8;
        if (t >= 4096) return;
        int f = t >> 6, l = t & 63;
        int row = (f >> 3) * 16 + (l & 15);
        int kk  = (f & 7) * 32 + (l >> 4) * 8;
        const float* Ws = W + row * 256 + kk;
        float4 a = *(const float4*)Ws, c = *(const float4*)(Ws + 4);
        uint4 r;
        r.x = pack2(a.x, a.y); r.y = pack2(a.z, a.w);
        r.z = pack2(c.x, c.y); r.w = pack2(c.z, c.w);
        ((uint4*)Wf)[t] = r;
    }
}

// ---------------- sharded CSR build ----------------

__global__ __launch_bounds__(256) void count_slot(
    const int* __restrict__ dst, int* dshard, int* __restrict__ slot,
    int n_pad, int n_edges)
{
    int e = blockIdx.x * 256 + threadIdx.x;
    if (e >= n_edges) return;
    int s = blockIdx.x & 7;
    int p = atomicAdd(dshard + s * n_pad + dst[e], 1);
    slot[e] = (p << 3) | s;
}

// fused: 8-shard totals -> deg; block LDS scan; atomic base allocation
// (segment ORDER is irrelevant for correctness — only disjointness matters);
// absolute shard bases written in the same pass.
__global__ __launch_bounds__(256) void combine_scan_atomic(
    int* dshard, int* __restrict__ deg, int* off, int* cursor,
    int n_pad, int n)
{
    __shared__ int tmp[256];
    __shared__ int sbase;
    int i = blockIdx.x * 256 + threadIdx.x;
    int cnt[8];
    int run = 0;
    if (i < n) {
#pragma unroll
        for (int s = 0; s < 8; ++s) {
            cnt[s] = dshard[s * n_pad + i];
            run += cnt[s];
        }
        deg[i] = run;
    }
    tmp[threadIdx.x] = run;
    __syncthreads();
    for (int s = 1; s < 256; s <<= 1) {
        int t = (threadIdx.x >= s) ? tmp[threadIdx.x - s] : 0;
        __syncthreads();
        tmp[threadIdx.x] += t;
        __syncthreads();
    }
    if (threadIdx.x == 255) sbase = atomicAdd(cursor, tmp[255]);
    __syncthreads();
    if (i < n) {
        int e = sbase + tmp[threadIdx.x] - run;   // exclusive start for node i
        off[i] = e;
#pragma unroll
        for (int s = 0; s < 8; ++s) {
            dshard[s * n_pad + i] = e;
            e += cnt[s];
        }
    }
}

__global__ __launch_bounds__(256) void fill2(
    const int* __restrict__ src, const int* __restrict__ dst,
    const int* __restrict__ slot, const int* __restrict__ dshard,
    int* __restrict__ edge_src, int n_pad, int n_edges)
{
    int e = blockIdx.x * 256 + threadIdx.x;
    if (e >= n_edges) return;
    int sp = slot[e];
    int pos = dshard[(sp & 7) * n_pad + dst[e]] + (sp >> 3);
    edge_src[pos] = src[e];
}

// ---- fused gather + MFMA GEMM: 16-row block, 16 edges in flight ----

__global__ __launch_bounds__(256) void sage_fused16(
    const unsigned short* __restrict__ xh, const int* __restrict__ edge_src,
    const int* __restrict__ off, const int* __restrict__ deg,
    const unsigned short* __restrict__ Wf, const float* __restrict__ bias,
    float* __restrict__ out, int n_nodes)
{
    __shared__ unsigned short sa[16 * LROW];   // one 16-row agg tile

    int wid  = threadIdx.x >> 6;
    int lane = threadIdx.x & 63;
    int g    = lane >> 4;          // edge sub-group 0..3
    int dl   = (lane & 15) * 8;    // bf16 slice start in row
    int m0   = blockIdx.x * 16;

    // ---- gather phase: wave wid -> rows wid*4 .. wid*4+3 ----
#pragma unroll
    for (int t = 0; t < 4; ++t) {
        int r = wid * 4 + t;
        int n = m0 + r;
        if (n < n_nodes) {
            int dg   = deg[n];
            int base = off[n];

            float s[8] = {0.f, 0.f, 0.f, 0.f, 0.f, 0.f, 0.f, 0.f};
            for (int j0 = 0; j0 < dg; j0 += 16) {
                int ja = j0 + g, jb = j0 + 4 + g, jc = j0 + 8 + g, jd = j0 + 12 + g;
                uint4 A = make_uint4(0u,0u,0u,0u), B = make_uint4(0u,0u,0u,0u);
                uint4 C = make_uint4(0u,0u,0u,0u), E = make_uint4(0u,0u,0u,0u);
                if (ja < dg) A = *(const uint4*)(xh + (long long)edge_src[base + ja] * 128 + dl);
                if (jb < dg) B = *(const uint4*)(xh + (long long)edge_src[base + jb] * 128 + dl);
                if (jc < dg) C = *(const uint4*)(xh + (long long)edge_src[base + jc] * 128 + dl);
                if (jd < dg) E = *(const uint4*)(xh + (long long)edge_src[base + jd] * 128 + dl);
                s[0] += __uint_as_float(A.x << 16) + __uint_as_float(B.x << 16)
                      + __uint_as_float(C.x << 16) + __uint_as_float(E.x << 16);
                s[1] += __uint_as_float(A.x & 0xFFFF0000u) + __uint_as_float(B.x & 0xFFFF0000u)
                      + __uint_as_float(C.x & 0xFFFF0000u) + __uint_as_float(E.x & 0xFFFF0000u);
                s[2] += __uint_as_float(A.y << 16) + __uint_as_float(B.y << 16)
                      + __uint_as_float(C.y << 16) + __uint_as_float(E.y << 16);
                s[3] += __uint_as_float(A.y & 0xFFFF0000u) + __uint_as_float(B.y & 0xFFFF0000u)
                      + __uint_as_float(C.y & 0xFFFF0000u) + __uint_as_float(E.y & 0xFFFF0000u);
                s[4] += __uint_as_float(A.z << 16) + __uint_as_float(B.z << 16)
                      + __uint_as_float(C.z << 16) + __uint_as_float(E.z << 16);
                s[5] += __uint_as_float(A.z & 0xFFFF0000u) + __uint_as_float(B.z & 0xFFFF0000u)
                      + __uint_as_float(C.z & 0xFFFF0000u) + __uint_as_float(E.z & 0xFFFF0000u);
                s[6] += __uint_as_float(A.w << 16) + __uint_as_float(B.w << 16)
                      + __uint_as_float(C.w << 16) + __uint_as_float(E.w << 16);
                s[7] += __uint_as_float(A.w & 0xFFFF0000u) + __uint_as_float(B.w & 0xFFFF0000u)
                      + __uint_as_float(C.w & 0xFFFF0000u) + __uint_as_float(E.w & 0xFFFF0000u);
            }
#pragma unroll
            for (int k = 0; k < 8; ++k) {
                s[k] += __shfl_xor(s[k], 16, 64);
                s[k] += __shfl_xor(s[k], 32, 64);
            }
            if (g == 0) {
                uint4 rr;
                if (dg > 0) {
                    float inv = 1.0f / (float)dg;
                    rr.x = pack2(s[0] * inv, s[1] * inv);
                    rr.y = pack2(s[2] * inv, s[3] * inv);
                    rr.z = pack2(s[4] * inv, s[5] * inv);
                    rr.w = pack2(s[6] * inv, s[7] * inv);
                } else {
                    rr = *(const uint4*)(xh + (long long)n * 128 + dl);
                }
                *(uint4*)(sa + r * LROW + dl) = rr;
            }
        }
    }
    __syncthreads();

    // ---- gemm phase: wave wid computes col-tiles nt = wid*2, wid*2+1 ----
    int arow = m0 + (lane & 15);
    if (arow >= n_nodes) arow = n_nodes - 1;   // clamp loads; stores guarded
    int ka = (lane >> 4) * 8;
    int lr = lane & 15;

    f32x4 acc[2] = {};
    const unsigned short* xr = xh + (long long)arow * 128;
    const bf16x8* WF = (const bf16x8*)Wf;
    int nt0 = wid * 2;

#pragma unroll
    for (int ks = 0; ks < 4; ++ks) {           // k = 0..127 (x half, global)
        bf16x8 af = *(const bf16x8*)(xr + ks * 32 + ka);
        acc[0] = __builtin_amdgcn_mfma_f32_16x16x32_bf16(af, WF[(nt0 * 8 + ks) * 64 + lane], acc[0], 0, 0, 0);
        acc[1] = __builtin_amdgcn_mfma_f32_16x16x32_bf16(af, WF[((nt0 + 1) * 8 + ks) * 64 + lane], acc[1], 0, 0, 0);
    }
#pragma unroll
    for (int ks = 0; ks < 4; ++ks) {           // k = 128..255 (agg half, LDS)
        bf16x8 af = *(const bf16x8*)(sa + lr * LROW + ks * 32 + ka);
        acc[0] = __builtin_amdgcn_mfma_f32_16x16x32_bf16(af, WF[(nt0 * 8 + 4 + ks) * 64 + lane], acc[0], 0, 0, 0);
        acc[1] = __builtin_amdgcn_mfma_f32_16x16x32_bf16(af, WF[((nt0 + 1) * 8 + 4 + ks) * 64 + lane], acc[1], 0, 0, 0);
    }

    int jn = lane & 15;
    int orow0 = m0 + (lane >> 4) * 4;
#pragma unroll
    for (int q = 0; q < 2; ++q) {
        int col = (nt0 + q) * 16 + jn;
        float bj = bias[col];
#pragma unroll
        for (int r = 0; r < 4; ++r) {
            int row = orow0 + r;
            if (row < n_nodes) {
                float v = acc[q][r] + bj;
                out[(long long)row * 128 + col] = v > 0.f ? v : 0.f;
            }
        }
    }
}

// ---------------- fp32 fallback kernels (round-8 proven) ----------------

__global__ __launch_bounds__(256) void edge_count(
    const int* __restrict__ dst, int* deg, int n_edges)
{
    int e = blockIdx.x * 256 + threadIdx.x;
    if (e < n_edges) atomicAdd(deg + dst[e], 1);
}

__global__ __launch_bounds__(256) void scan_a(
    const int* __restrict__ deg, int* off, int* bsum, int n)
{
    __shared__ int tmp[256];
    int i = blockIdx.x * 256 + threadIdx.x;
    int v = (i < n) ? deg[i] : 0;
    tmp[threadIdx.x] = v;
    __syncthreads();
    for (int s = 1; s < 256; s <<= 1) {
        int t = (threadIdx.x >= s) ? tmp[threadIdx.x - s] : 0;
        __syncthreads();
        tmp[threadIdx.x] += t;
        __syncthreads();
    }
    if (i < n) off[i] = tmp[threadIdx.x];
    if (threadIdx.x == 255) bsum[blockIdx.x] = tmp[255];
}

__global__ __launch_bounds__(256) void scan_b(int* bsum, int nb)
{
    __shared__ int tmp[256];
    int v = (threadIdx.x < nb) ? bsum[threadIdx.x] : 0;
    tmp[threadIdx.x] = v;
    __syncthreads();
    for (int s = 1; s < 256; s <<= 1) {
        int t = (threadIdx.x >= s) ? tmp[threadIdx.x - s] : 0;
        __syncthreads();
        tmp[threadIdx.x] += t;
        __syncthreads();
    }
    if (threadIdx.x < nb) bsum[threadIdx.x] = tmp[threadIdx.x];
}

__global__ __launch_bounds__(256) void scan_c(
    const int* __restrict__ deg, const int* __restrict__ bsum,
    int* off, int* cursor, int n)
{
    int i = blockIdx.x * 256 + threadIdx.x;
    if (i >= n) return;
    int add = (blockIdx.x > 0) ? bsum[blockIdx.x - 1] : 0;
    int e = off[i] - deg[i] + add;
    off[i] = e;
    cursor[i] = e;
}

__global__ __launch_bounds__(256) void edge_fill(
    const int* __restrict__ src, const int* __restrict__ dst,
    int* cursor, int* edge_src, int n_edges)
{
    int e = blockIdx.x * 256 + threadIdx.x;
    if (e < n_edges) {
        int p = atomicAdd(cursor + dst[e], 1);
        edge_src[p] = src[e];
    }
}

__global__ __launch_bounds__(256) void sage_gather(
    const float* __restrict__ x, const int* __restrict__ edge_src,
    const int* __restrict__ off, const int* __restrict__ deg,
    float* __restrict__ agg, int n_nodes)
{
    int wid  = threadIdx.x >> 6;
    int lane = threadIdx.x & 63;
    int n = blockIdx.x * 4 + wid;
    if (n >= n_nodes) return;
    int dg   = deg[n];
    int base = off[n];
    const float2* X2 = (const float2*)x;

    float sx = 0.f, sy = 0.f;
    int j = 0;
    for (; j + 1 < dg; j += 2) {
        int s0 = edge_src[base + j];
        int s1 = edge_src[base + j + 1];
        float2 a = X2[(long long)s0 * 64 + lane];
        float2 c = X2[(long long)s1 * 64 + lane];
        sx += a.x + c.x;
        sy += a.y + c.y;
    }
    if (j < dg) {
        float2 a = X2[(long long)edge_src[base + j] * 64 + lane];
        sx += a.x; sy += a.y;
    }
    float2 r;
    if (dg > 0) {
        float inv = 1.0f / (float)dg;
        r.x = sx * inv; r.y = sy * inv;
    } else {
        r = X2[(long long)n * 64 + lane];
    }
    ((float2*)agg)[(long long)n * 64 + lane] = r;
}

__global__ __launch_bounds__(256) void sage_scatter(
    const float* __restrict__ x, const int* __restrict__ src,
    const int* __restrict__ dst, float* out_sum, int* deg, int n_edges)
{
    long long gid = (long long)blockIdx.x * 256 + threadIdx.x;
    long long total = (long long)n_edges * 32;
    if (gid >= total) return;
    int e  = (int)(gid >> 5);
    int d4 = (int)(gid & 31);
    int s  = src[e];
    int dd = dst[e];
    float4 xv = ((const float4*)x)[s * 32 + d4];
    float* o = out_sum + (long long)dd * D + d4 * 4;
    atomicAdd(o + 0, xv.x);
    atomicAdd(o + 1, xv.y);
    atomicAdd(o + 2, xv.z);
    atomicAdd(o + 3, xv.w);
    if (d4 == 0) atomicAdd(deg + dd, 1);
}

__global__ __launch_bounds__(256) void sage_finalize(
    const float* __restrict__ x, const int* __restrict__ deg,
    float* out, int n_nodes)
{
    int gid = blockIdx.x * 256 + threadIdx.x;
    int total = n_nodes * 32;
    if (gid >= total) return;
    int n = gid >> 5;
    int dg = deg[n];
    float4 v = ((float4*)out)[gid];
    if (dg > 0) {
        float inv = 1.0f / (float)dg;
        v.x *= inv; v.y *= inv; v.z *= inv; v.w *= inv;
    } else {
        v = ((const float4*)x)[gid];
    }
    ((float4*)out)[gid] = v;
}

__global__ __launch_bounds__(256) void sage_gemm(
    const float* __restrict__ x, const float* __restrict__ W,
    const float* __restrict__ b, const float* agg, float* out, int n_nodes)
{
    __shared__ float4 sx[NT * 32];
    __shared__ float4 sa2[NT * 32];

    int tid = threadIdx.x;
    int base_row = blockIdx.x * NT;

    for (int i = tid; i < NT * 32; i += 256) {
        int r = i >> 5, c = i & 31;
        int n = base_row + r; if (n >= n_nodes) n = n_nodes - 1;
        sx[i] = ((const float4*)x)[(long long)n * 32 + c];
        sa2[i] = ((const float4*)agg)[(long long)n * 32 + c];
    }
    __syncthreads();

    int j   = tid & 127;
    int sub = tid >> 7;
    int rbase = sub * NTT;

    const float4* W4 = (const float4*)W;
    float acc[NTT];
#pragma unroll
    for (int i = 0; i < NTT; ++i) acc[i] = 0.f;

#pragma unroll 4
    for (int k4 = 0; k4 < 32; ++k4) {
        float4 wx = W4[j * 64 + k4];
        float4 wa = W4[j * 64 + 32 + k4];
#pragma unroll
        for (int nn = 0; nn < NTT; ++nn) {
            float4 hx = sx[(rbase + nn) * 32 + k4];
            float4 ha = sa2[(rbase + nn) * 32 + k4];
            acc[nn] += wx.x * hx.x + wx.y * hx.y + wx.z * hx.z + wx.w * hx.w
                     + wa.x * ha.x + wa.y * ha.y + wa.z * ha.z + wa.w * ha.w;
        }
    }

    float bj = b[j];
#pragma unroll
    for (int nn = 0; nn < NTT; ++nn) {
        int n = base_row + rbase + nn;
        if (n < n_nodes) {
            float v = acc[nn] + bj;
            out[(long long)n * D + j] = v > 0.f ? v : 0.f;
        }
    }
}

extern "C" void kernel_launch(void* const* d_in, const int* in_sizes, int n_in,
                              void* d_out, int out_size, void* d_ws, size_t ws_size,
                              hipStream_t stream) {
    const float* x  = (const float*)d_in[0];
    const float* W  = (const float*)d_in[1];
    const float* b  = (const float*)d_in[2];
    const int* src  = (const int*)d_in[3];
    const int* dst  = (const int*)d_in[4];
    float* out = (float*)d_out;

    int n_nodes = in_sizes[0] / D;
    int n_edges = in_sizes[3];

    int n_pad = (n_nodes + 255) & ~255;
    int e_pad = (n_edges + 3) & ~3;
    int nblocks_scan = (n_nodes + 255) / 256;

    // ws layout (ints): dshard(8*n_pad) | slot(e_pad) | off(n_pad) | deg(n_pad)
    //                 | bsum(1024) | edge_src(e_pad)
    //   then (bf16): x_bf16 (N*128) | W_frag(32768)
    size_t need_csr  = ((size_t)10 * n_pad + 2 * (size_t)e_pad + 1024) * sizeof(int);
    size_t need_bf16 = need_csr + ((size_t)n_nodes * D + 32768) * sizeof(unsigned short);
    bool scan_ok = (nblocks_scan <= 256);
    bool bf16_ok = scan_ok && (ws_size >= need_bf16);
    bool csr_ok  = scan_ok && (ws_size >= need_csr);

    int* dshard   = (int*)d_ws;               // 8*n_pad
    int* slot     = dshard + 8 * (size_t)n_pad;
    int* off      = slot + e_pad;
    int* deg      = off + n_pad;
    int* bsum     = deg + n_pad;               // bsum[0] doubles as cursor (bf16 path)
    int* edge_src = bsum + 1024;

    int eblocks = (n_edges + 255) / 256;

    if (bf16_ok) {
        unsigned short* xh = (unsigned short*)(edge_src + e_pad);
        unsigned short* Wf = xh + (size_t)n_nodes * D;
        int* cursor = bsum;

        // fused: zero dshard+cursor + x->bf16 + W->fragment-order bf16
        int x8 = n_nodes * D / 8;
        int ndz4 = (8 * n_pad) / 4;
        convert_k<<<(x8 + 4096 + 255) / 256, 256, 0, stream>>>(
            x, W, xh, Wf, dshard, cursor, ndz4, x8);

        // sharded CSR build (3 kernels)
        count_slot<<<eblocks, 256, 0, stream>>>(dst, dshard, slot, n_pad, n_edges);
        combine_scan_atomic<<<nblocks_scan, 256, 0, stream>>>(
            dshard, deg, off, cursor, n_pad, n_nodes);
        fill2<<<eblocks, 256, 0, stream>>>(src, dst, slot, dshard, edge_src, n_pad, n_edges);

        // fused gather + MFMA GEMM (16-row blocks, 16-deep gather MLP)
        sage_fused16<<<(n_nodes + 15) / 16, 256, 0, stream>>>(
            xh, edge_src, off, deg, Wf, b, out, n_nodes);
    } else if (csr_ok) {
        // fp32 CSR fallback (round-8 path, non-sharded)
        int* cursor = slot;   // reuse
        hipMemsetAsync(deg, 0, (size_t)n_nodes * sizeof(int), stream);
        edge_count<<<eblocks, 256, 0, stream>>>(dst, deg, n_edges);
        scan_a<<<nblocks_scan, 256, 0, stream>>>(deg, off, bsum, n_nodes);
        scan_b<<<1, 256, 0, stream>>>(bsum, nblocks_scan);
        scan_c<<<nblocks_scan, 256, 0, stream>>>(deg, bsum, off, cursor, n_nodes);
        edge_fill<<<eblocks, 256, 0, stream>>>(src, dst, cursor, edge_src, n_edges);
        sage_gather<<<(n_nodes + 3) / 4, 256, 0, stream>>>(
            x, edge_src, off, deg, out, n_nodes);
        int blocks = (n_nodes + NT - 1) / NT;
        sage_gemm<<<blocks, 256, 0, stream>>>(x, W, b, out, out, n_nodes);
    } else {
        hipMemsetAsync(d_out, 0, (size_t)out_size * sizeof(float), stream);
        hipMemsetAsync(deg, 0, (size_t)n_nodes * sizeof(int), stream);
        long long total = (long long)n_edges * 32;
        int blocks = (int)((total + 255) / 256);
        sage_scatter<<<blocks, 256, 0, stream>>>(x, src, dst, out, deg, n_edges);
        int fblocks = (n_nodes * 32 + 255) / 256;
        sage_finalize<<<fblocks, 256, 0, stream>>>(x, deg, out, n_nodes);
        int gb = (n_nodes + NT - 1) / NT;
        sage_gemm<<<gb, 256, 0, stream>>>(x, W, b, out, out, n_nodes);
    }
}

// Round 19
// 92.911 us; speedup vs baseline: 1.3111x; 1.0125x over previous
//
#include <hip/hip_runtime.h>

// GraphSAGE layer: out = relu([x, mean-agg(x[src]->dst)] @ W^T + b)
// N=50000 nodes, E=600000 edges, D=128.
//
// Round 19: group-per-node gather inside fused16.
//  Round 16/18 A/B showed gather is NOT unroll-depth-limited; the wave's 4
//  nodes were gathered serially (4 dependent chains) with 16 shfl/node.
//  Now each 16-lane group owns one node: 4 concurrent chains per wave,
//  lane-local accumulation (zero shfl), same per-inst memory footprint.
// CSR sharded build (3 kernels) + gemm phase proven rounds 16-18.
// Fallbacks: fp32 CSR, fp-atomic.

#define D 128
#define NT 32
#define NTT 16
#define LROW 136   // padded LDS row stride in bf16 (272 B)

typedef short bf16x8 __attribute__((ext_vector_type(8)));
typedef float f32x4 __attribute__((ext_vector_type(4)));

__device__ __forceinline__ unsigned bf16_rne(float f) {
    unsigned u = __float_as_uint(f);
    return (u + 0x7FFFu + ((u >> 16) & 1u)) >> 16;
}
__device__ __forceinline__ unsigned pack2(float lo, float hi) {
    return bf16_rne(lo) | (bf16_rne(hi) << 16);
}

// --- fused: zero dshard+cursor + convert x -> xh + convert W -> Wf ---

__global__ __launch_bounds__(256) void convert_k(
    const float* __restrict__ x, const float* __restrict__ W,
    unsigned short* __restrict__ xh, unsigned short* __restrict__ Wf,
    int* __restrict__ dshard, int* __restrict__ cursor, int ndz4, int x8)
{
    int i = blockIdx.x * 256 + threadIdx.x;
    if (i == 0) *cursor = 0;
    if (i < ndz4) ((int4*)dshard)[i] = make_int4(0, 0, 0, 0);
    if (i < x8) {
        const float4* I = (const float4*)x;
        float4 a = I[2 * i], c = I[2 * i + 1];
        uint4 r;
        r.x = pack2(a.x, a.y); r.y = pack2(a.z, a.w);
        r.z = pack2(c.x, c.y); r.w = pack2(c.z, c.w);
        ((uint4*)xh)[i] = r;
    } else {
        int t = i - x8;
        if (t >= 4096) return;
        int f = t >> 6, l = t & 63;
        int row = (f >> 3) * 16 + (l & 15);
        int kk  = (f & 7) * 32 + (l >> 4) * 8;
        const float* Ws = W + row * 256 + kk;
        float4 a = *(const float4*)Ws, c = *(const float4*)(Ws + 4);
        uint4 r;
        r.x = pack2(a.x, a.y); r.y = pack2(a.z, a.w);
        r.z = pack2(c.x, c.y); r.w = pack2(c.z, c.w);
        ((uint4*)Wf)[t] = r;
    }
}

// ---------------- sharded CSR build ----------------

__global__ __launch_bounds__(256) void count_slot(
    const int* __restrict__ dst, int* dshard, int* __restrict__ slot,
    int n_pad, int n_edges)
{
    int e = blockIdx.x * 256 + threadIdx.x;
    if (e >= n_edges) return;
    int s = blockIdx.x & 7;
    int p = atomicAdd(dshard + s * n_pad + dst[e], 1);
    slot[e] = (p << 3) | s;
}

// fused: 8-shard totals -> deg; block LDS scan; atomic base allocation.
__global__ __launch_bounds__(256) void combine_scan_atomic(
    int* dshard, int* __restrict__ deg, int* off, int* cursor,
    int n_pad, int n)
{
    __shared__ int tmp[256];
    __shared__ int sbase;
    int i = blockIdx.x * 256 + threadIdx.x;
    int cnt[8];
    int run = 0;
    if (i < n) {
#pragma unroll
        for (int s = 0; s < 8; ++s) {
            cnt[s] = dshard[s * n_pad + i];
            run += cnt[s];
        }
        deg[i] = run;
    }
    tmp[threadIdx.x] = run;
    __syncthreads();
    for (int s = 1; s < 256; s <<= 1) {
        int t = (threadIdx.x >= s) ? tmp[threadIdx.x - s] : 0;
        __syncthreads();
        tmp[threadIdx.x] += t;
        __syncthreads();
    }
    if (threadIdx.x == 255) sbase = atomicAdd(cursor, tmp[255]);
    __syncthreads();
    if (i < n) {
        int e = sbase + tmp[threadIdx.x] - run;   // exclusive start for node i
        off[i] = e;
#pragma unroll
        for (int s = 0; s < 8; ++s) {
            dshard[s * n_pad + i] = e;
            e += cnt[s];
        }
    }
}

__global__ __launch_bounds__(256) void fill2(
    const int* __restrict__ src, const int* __restrict__ dst,
    const int* __restrict__ slot, const int* __restrict__ dshard,
    int* __restrict__ edge_src, int n_pad, int n_edges)
{
    int e = blockIdx.x * 256 + threadIdx.x;
    if (e >= n_edges) return;
    int sp = slot[e];
    int pos = dshard[(sp & 7) * n_pad + dst[e]] + (sp >> 3);
    edge_src[pos] = src[e];
}

// ---- fused gather + MFMA GEMM: 16-row block, group-per-node gather ----

__global__ __launch_bounds__(256) void sage_fused16(
    const unsigned short* __restrict__ xh, const int* __restrict__ edge_src,
    const int* __restrict__ off, const int* __restrict__ deg,
    const unsigned short* __restrict__ Wf, const float* __restrict__ bias,
    float* __restrict__ out, int n_nodes)
{
    __shared__ unsigned short sa[16 * LROW];   // one 16-row agg tile

    int wid  = threadIdx.x >> 6;
    int lane = threadIdx.x & 63;
    int g    = lane >> 4;          // group 0..3 -> one NODE per group
    int dl   = (lane & 15) * 8;    // bf16 slice start in row
    int m0   = blockIdx.x * 16;

    // ---- gather phase: group g of wave wid owns row r = wid*4+g ----
    {
        int r = wid * 4 + g;
        int n = m0 + r;
        if (n < n_nodes) {
            int dg   = deg[n];
            int base = off[n];

            float s[8] = {0.f, 0.f, 0.f, 0.f, 0.f, 0.f, 0.f, 0.f};
            for (int j0 = 0; j0 < dg; j0 += 4) {   // 4 edges in flight per group
                uint4 A = make_uint4(0u,0u,0u,0u), B = make_uint4(0u,0u,0u,0u);
                uint4 C = make_uint4(0u,0u,0u,0u), E = make_uint4(0u,0u,0u,0u);
                A = *(const uint4*)(xh + (long long)edge_src[base + j0] * 128 + dl);
                if (j0 + 1 < dg) B = *(const uint4*)(xh + (long long)edge_src[base + j0 + 1] * 128 + dl);
                if (j0 + 2 < dg) C = *(const uint4*)(xh + (long long)edge_src[base + j0 + 2] * 128 + dl);
                if (j0 + 3 < dg) E = *(const uint4*)(xh + (long long)edge_src[base + j0 + 3] * 128 + dl);
                s[0] += __uint_as_float(A.x << 16) + __uint_as_float(B.x << 16)
                      + __uint_as_float(C.x << 16) + __uint_as_float(E.x << 16);
                s[1] += __uint_as_float(A.x & 0xFFFF0000u) + __uint_as_float(B.x & 0xFFFF0000u)
                      + __uint_as_float(C.x & 0xFFFF0000u) + __uint_as_float(E.x & 0xFFFF0000u);
                s[2] += __uint_as_float(A.y << 16) + __uint_as_float(B.y << 16)
                      + __uint_as_float(C.y << 16) + __uint_as_float(E.y << 16);
                s[3] += __uint_as_float(A.y & 0xFFFF0000u) + __uint_as_float(B.y & 0xFFFF0000u)
                      + __uint_as_float(C.y & 0xFFFF0000u) + __uint_as_float(E.y & 0xFFFF0000u);
                s[4] += __uint_as_float(A.z << 16) + __uint_as_float(B.z << 16)
                      + __uint_as_float(C.z << 16) + __uint_as_float(E.z << 16);
                s[5] += __uint_as_float(A.z & 0xFFFF0000u) + __uint_as_float(B.z & 0xFFFF0000u)
                      + __uint_as_float(C.z & 0xFFFF0000u) + __uint_as_float(E.z & 0xFFFF0000u);
                s[6] += __uint_as_float(A.w << 16) + __uint_as_float(B.w << 16)
                      + __uint_as_float(C.w << 16) + __uint_as_float(E.w << 16);
                s[7] += __uint_as_float(A.w & 0xFFFF0000u) + __uint_as_float(B.w & 0xFFFF0000u)
                      + __uint_as_float(C.w & 0xFFFF0000u) + __uint_as_float(E.w & 0xFFFF0000u);
            }
            uint4 rr;
            if (dg > 0) {
                float inv = 1.0f / (float)dg;
                rr.x = pack2(s[0] * inv, s[1] * inv);
                rr.y = pack2(s[2] * inv, s[3] * inv);
                rr.z = pack2(s[4] * inv, s[5] * inv);
                rr.w = pack2(s[6] * inv, s[7] * inv);
            } else {
                rr = *(const uint4*)(xh + (long long)n * 128 + dl);
            }
            *(uint4*)(sa + r * LROW + dl) = rr;    // lane-local: no shfl needed
        }
    }
    __syncthreads();

    // ---- gemm phase: wave wid computes col-tiles nt = wid*2, wid*2+1 ----
    int arow = m0 + (lane & 15);
    if (arow >= n_nodes) arow = n_nodes - 1;   // clamp loads; stores guarded
    int ka = (lane >> 4) * 8;
    int lr = lane & 15;

    f32x4 acc[2] = {};
    const unsigned short* xr = xh + (long long)arow * 128;
    const bf16x8* WF = (const bf16x8*)Wf;
    int nt0 = wid * 2;

#pragma unroll
    for (int ks = 0; ks < 4; ++ks) {           // k = 0..127 (x half, global)
        bf16x8 af = *(const bf16x8*)(xr + ks * 32 + ka);
        acc[0] = __builtin_amdgcn_mfma_f32_16x16x32_bf16(af, WF[(nt0 * 8 + ks) * 64 + lane], acc[0], 0, 0, 0);
        acc[1] = __builtin_amdgcn_mfma_f32_16x16x32_bf16(af, WF[((nt0 + 1) * 8 + ks) * 64 + lane], acc[1], 0, 0, 0);
    }
#pragma unroll
    for (int ks = 0; ks < 4; ++ks) {           // k = 128..255 (agg half, LDS)
        bf16x8 af = *(const bf16x8*)(sa + lr * LROW + ks * 32 + ka);
        acc[0] = __builtin_amdgcn_mfma_f32_16x16x32_bf16(af, WF[(nt0 * 8 + 4 + ks) * 64 + lane], acc[0], 0, 0, 0);
        acc[1] = __builtin_amdgcn_mfma_f32_16x16x32_bf16(af, WF[((nt0 + 1) * 8 + 4 + ks) * 64 + lane], acc[1], 0, 0, 0);
    }

    int jn = lane & 15;
    int orow0 = m0 + (lane >> 4) * 4;
#pragma unroll
    for (int q = 0; q < 2; ++q) {
        int col = (nt0 + q) * 16 + jn;
        float bj = bias[col];
#pragma unroll
        for (int r = 0; r < 4; ++r) {
            int row = orow0 + r;
            if (row < n_nodes) {
                float v = acc[q][r] + bj;
                out[(long long)row * 128 + col] = v > 0.f ? v : 0.f;
            }
        }
    }
}

// ---------------- fp32 fallback kernels (round-8 proven) ----------------

__global__ __launch_bounds__(256) void edge_count(
    const int* __restrict__ dst, int* deg, int n_edges)
{
    int e = blockIdx.x * 256 + threadIdx.x;
    if (e < n_edges) atomicAdd(deg + dst[e], 1);
}

__global__ __launch_bounds__(256) void scan_a(
    const int* __restrict__ deg, int* off, int* bsum, int n)
{
    __shared__ int tmp[256];
    int i = blockIdx.x * 256 + threadIdx.x;
    int v = (i < n) ? deg[i] : 0;
    tmp[threadIdx.x] = v;
    __syncthreads();
    for (int s = 1; s < 256; s <<= 1) {
        int t = (threadIdx.x >= s) ? tmp[threadIdx.x - s] : 0;
        __syncthreads();
        tmp[threadIdx.x] += t;
        __syncthreads();
    }
    if (i < n) off[i] = tmp[threadIdx.x];
    if (threadIdx.x == 255) bsum[blockIdx.x] = tmp[255];
}

__global__ __launch_bounds__(256) void scan_b(int* bsum, int nb)
{
    __shared__ int tmp[256];
    int v = (threadIdx.x < nb) ? bsum[threadIdx.x] : 0;
    tmp[threadIdx.x] = v;
    __syncthreads();
    for (int s = 1; s < 256; s <<= 1) {
        int t = (threadIdx.x >= s) ? tmp[threadIdx.x - s] : 0;
        __syncthreads();
        tmp[threadIdx.x] += t;
        __syncthreads();
    }
    if (threadIdx.x < nb) bsum[threadIdx.x] = tmp[threadIdx.x];
}

__global__ __launch_bounds__(256) void scan_c(
    const int* __restrict__ deg, const int* __restrict__ bsum,
    int* off, int* cursor, int n)
{
    int i = blockIdx.x * 256 + threadIdx.x;
    if (i >= n) return;
    int add = (blockIdx.x > 0) ? bsum[blockIdx.x - 1] : 0;
    int e = off[i] - deg[i] + add;
    off[i] = e;
    cursor[i] = e;
}

__global__ __launch_bounds__(256) void edge_fill(
    const int* __restrict__ src, const int* __restrict__ dst,
    int* cursor, int* edge_src, int n_edges)
{
    int e = blockIdx.x * 256 + threadIdx.x;
    if (e < n_edges) {
        int p = atomicAdd(cursor + dst[e], 1);
        edge_src[p] = src[e];
    }
}

__global__ __launch_bounds__(256) void sage_gather(
    const float* __restrict__ x, const int* __restrict__ edge_src,
    const int* __restrict__ off, const int* __restrict__ deg,
    float* __restrict__ agg, int n_nodes)
{
    int wid  = threadIdx.x >> 6;
    int lane = threadIdx.x & 63;
    int n = blockIdx.x * 4 + wid;
    if (n >= n_nodes) return;
    int dg   = deg[n];
    int base = off[n];
    const float2* X2 = (const float2*)x;

    float sx = 0.f, sy = 0.f;
    int j = 0;
    for (; j + 1 < dg; j += 2) {
        int s0 = edge_src[base + j];
        int s1 = edge_src[base + j + 1];
        float2 a = X2[(long long)s0 * 64 + lane];
        float2 c = X2[(long long)s1 * 64 + lane];
        sx += a.x + c.x;
        sy += a.y + c.y;
    }
    if (j < dg) {
        float2 a = X2[(long long)edge_src[base + j] * 64 + lane];
        sx += a.x; sy += a.y;
    }
    float2 r;
    if (dg > 0) {
        float inv = 1.0f / (float)dg;
        r.x = sx * inv; r.y = sy * inv;
    } else {
        r = X2[(long long)n * 64 + lane];
    }
    ((float2*)agg)[(long long)n * 64 + lane] = r;
}

__global__ __launch_bounds__(256) void sage_scatter(
    const float* __restrict__ x, const int* __restrict__ src,
    const int* __restrict__ dst, float* out_sum, int* deg, int n_edges)
{
    long long gid = (long long)blockIdx.x * 256 + threadIdx.x;
    long long total = (long long)n_edges * 32;
    if (gid >= total) return;
    int e  = (int)(gid >> 5);
    int d4 = (int)(gid & 31);
    int s  = src[e];
    int dd = dst[e];
    float4 xv = ((const float4*)x)[s * 32 + d4];
    float* o = out_sum + (long long)dd * D + d4 * 4;
    atomicAdd(o + 0, xv.x);
    atomicAdd(o + 1, xv.y);
    atomicAdd(o + 2, xv.z);
    atomicAdd(o + 3, xv.w);
    if (d4 == 0) atomicAdd(deg + dd, 1);
}

__global__ __launch_bounds__(256) void sage_finalize(
    const float* __restrict__ x, const int* __restrict__ deg,
    float* out, int n_nodes)
{
    int gid = blockIdx.x * 256 + threadIdx.x;
    int total = n_nodes * 32;
    if (gid >= total) return;
    int n = gid >> 5;
    int dg = deg[n];
    float4 v = ((float4*)out)[gid];
    if (dg > 0) {
        float inv = 1.0f / (float)dg;
        v.x *= inv; v.y *= inv; v.z *= inv; v.w *= inv;
    } else {
        v = ((const float4*)x)[gid];
    }
    ((float4*)out)[gid] = v;
}

__global__ __launch_bounds__(256) void sage_gemm(
    const float* __restrict__ x, const float* __restrict__ W,
    const float* __restrict__ b, const float* agg, float* out, int n_nodes)
{
    __shared__ float4 sx[NT * 32];
    __shared__ float4 sa2[NT * 32];

    int tid = threadIdx.x;
    int base_row = blockIdx.x * NT;

    for (int i = tid; i < NT * 32; i += 256) {
        int r = i >> 5, c = i & 31;
        int n = base_row + r; if (n >= n_nodes) n = n_nodes - 1;
        sx[i] = ((const float4*)x)[(long long)n * 32 + c];
        sa2[i] = ((const float4*)agg)[(long long)n * 32 + c];
    }
    __syncthreads();

    int j   = tid & 127;
    int sub = tid >> 7;
    int rbase = sub * NTT;

    const float4* W4 = (const float4*)W;
    float acc[NTT];
#pragma unroll
    for (int i = 0; i < NTT; ++i) acc[i] = 0.f;

#pragma unroll 4
    for (int k4 = 0; k4 < 32; ++k4) {
        float4 wx = W4[j * 64 + k4];
        float4 wa = W4[j * 64 + 32 + k4];
#pragma unroll
        for (int nn = 0; nn < NTT; ++nn) {
            float4 hx = sx[(rbase + nn) * 32 + k4];
            float4 ha = sa2[(rbase + nn) * 32 + k4];
            acc[nn] += wx.x * hx.x + wx.y * hx.y + wx.z * hx.z + wx.w * hx.w
                     + wa.x * ha.x + wa.y * ha.y + wa.z * ha.z + wa.w * ha.w;
        }
    }

    float bj = b[j];
#pragma unroll
    for (int nn = 0; nn < NTT; ++nn) {
        int n = base_row + rbase + nn;
        if (n < n_nodes) {
            float v = acc[nn] + bj;
            out[(long long)n * D + j] = v > 0.f ? v : 0.f;
        }
    }
}

extern "C" void kernel_launch(void* const* d_in, const int* in_sizes, int n_in,
                              void* d_out, int out_size, void* d_ws, size_t ws_size,
                              hipStream_t stream) {
    const float* x  = (const float*)d_in[0];
    const float* W  = (const float*)d_in[1];
    const float* b  = (const float*)d_in[2];
    const int* src  = (const int*)d_in[3];
    const int* dst  = (const int*)d_in[4];
    float* out = (float*)d_out;

    int n_nodes = in_sizes[0] / D;
    int n_edges = in_sizes[3];

    int n_pad = (n_nodes + 255) & ~255;
    int e_pad = (n_edges + 3) & ~3;
    int nblocks_scan = (n_nodes + 255) / 256;

    // ws layout (ints): dshard(8*n_pad) | slot(e_pad) | off(n_pad) | deg(n_pad)
    //                 | bsum(1024) | edge_src(e_pad)
    //   then (bf16): x_bf16 (N*128) | W_frag(32768)
    size_t need_csr  = ((size_t)10 * n_pad + 2 * (size_t)e_pad + 1024) * sizeof(int);
    size_t need_bf16 = need_csr + ((size_t)n_nodes * D + 32768) * sizeof(unsigned short);
    bool scan_ok = (nblocks_scan <= 256);
    bool bf16_ok = scan_ok && (ws_size >= need_bf16);
    bool csr_ok  = scan_ok && (ws_size >= need_csr);

    int* dshard   = (int*)d_ws;               // 8*n_pad
    int* slot     = dshard + 8 * (size_t)n_pad;
    int* off      = slot + e_pad;
    int* deg      = off + n_pad;
    int* bsum     = deg + n_pad;               // bsum[0] doubles as cursor (bf16 path)
    int* edge_src = bsum + 1024;

    int eblocks = (n_edges + 255) / 256;

    if (bf16_ok) {
        unsigned short* xh = (unsigned short*)(edge_src + e_pad);
        unsigned short* Wf = xh + (size_t)n_nodes * D;
        int* cursor = bsum;

        // fused: zero dshard+cursor + x->bf16 + W->fragment-order bf16
        int x8 = n_nodes * D / 8;
        int ndz4 = (8 * n_pad) / 4;
        convert_k<<<(x8 + 4096 + 255) / 256, 256, 0, stream>>>(
            x, W, xh, Wf, dshard, cursor, ndz4, x8);

        // sharded CSR build (3 kernels)
        count_slot<<<eblocks, 256, 0, stream>>>(dst, dshard, slot, n_pad, n_edges);
        combine_scan_atomic<<<nblocks_scan, 256, 0, stream>>>(
            dshard, deg, off, cursor, n_pad, n_nodes);
        fill2<<<eblocks, 256, 0, stream>>>(src, dst, slot, dshard, edge_src, n_pad, n_edges);

        // fused gather + MFMA GEMM (16-row blocks, group-per-node gather)
        sage_fused16<<<(n_nodes + 15) / 16, 256, 0, stream>>>(
            xh, edge_src, off, deg, Wf, b, out, n_nodes);
    } else if (csr_ok) {
        // fp32 CSR fallback (round-8 path, non-sharded)
        int* cursor = slot;   // reuse
        hipMemsetAsync(deg, 0, (size_t)n_nodes * sizeof(int), stream);
        edge_count<<<eblocks, 256, 0, stream>>>(dst, deg, n_edges);
        scan_a<<<nblocks_scan, 256, 0, stream>>>(deg, off, bsum, n_nodes);
        scan_b<<<1, 256, 0, stream>>>(bsum, nblocks_scan);
        scan_c<<<nblocks_scan, 256, 0, stream>>>(deg, bsum, off, cursor, n_nodes);
        edge_fill<<<eblocks, 256, 0, stream>>>(src, dst, cursor, edge_src, n_edges);
        sage_gather<<<(n_nodes + 3) / 4, 256, 0, stream>>>(
            x, edge_src, off, deg, out, n_nodes);
        int blocks = (n_nodes + NT - 1) / NT;
        sage_gemm<<<blocks, 256, 0, stream>>>(x, W, b, out, out, n_nodes);
    } else {
        hipMemsetAsync(d_out, 0, (size_t)out_size * sizeof(float), stream);
        hipMemsetAsync(deg, 0, (size_t)n_nodes * sizeof(int), stream);
        long long total = (long long)n_edges * 32;
        int blocks = (int)((total + 255) / 256);
        sage_scatter<<<blocks, 256, 0, stream>>>(x, src, dst, out, deg, n_edges);
        int fblocks = (n_nodes * 32 + 255) / 256;
        sage_finalize<<<fblocks, 256, 0, stream>>>(x, deg, out, n_nodes);
        int gb = (n_nodes + NT - 1) / NT;
        sage_gemm<<<gb, 256, 0, stream>>>(x, W, b, out, out, n_nodes);
    }
}